// Round 11
// baseline (523.643 us; speedup 1.0000x reference)
//
#include <hip/hip_runtime.h>

#define HSZ 32
#define TT  1024
#define LOG2E 1.44269504088896340736f

typedef _Float16     h2  __attribute__((ext_vector_type(2)));
typedef unsigned int v4u __attribute__((ext_vector_type(4)));

__device__ __forceinline__ float frcp(float x)  { return __builtin_amdgcn_rcpf(x); }
__device__ __forceinline__ float fexp2(float x) { return __builtin_amdgcn_exp2f(x); }
__device__ __forceinline__ h2    bch2(unsigned int u) { return __builtin_bit_cast(h2, u); }
__device__ __forceinline__ float fdot2(h2 a, h2 b, float c) {
  return __builtin_amdgcn_fdot2(a, b, c, false);
}

// -------- prep: prescale rows, round to f16, pack lane-major (proven R7) ----
// Lane l = half*32+j owns rows r1 = (half?2:0)*32+j (i|g), r2 = (half?3:1)*32+j
// (f|o). Row r1 scaled by s1 (-2log2e for g, -log2e else), r2 by s2 = -log2e,
// THEN rounded to f16 pairs. Per-lane ws block: 36 dwords (144 B):
//   [0..15] = r1 as 16 half2 k-pairs   [16..31] = r2 as 16 half2 k-pairs
//   [32..35] = f32 { s1*(b_ih[r1]+b_hh[r1]), s2*(b_ih[r2]+b_hh[r2]),
//                    s1*W_ih[r1], s2*W_ih[r2] }
__global__ void lstm_prep_kernel(const float* __restrict__ W_ih,
                                 const float* __restrict__ W_hh,
                                 const float* __restrict__ b_ih,
                                 const float* __restrict__ b_hh,
                                 unsigned int* __restrict__ ws)
{
  const int lane = threadIdx.x;        // 0..63
  const int half = lane >> 5;
  const int j    = lane & 31;
  const int r1 = (half ? 2 : 0) * HSZ + j;
  const int r2 = (half ? 3 : 1) * HSZ + j;
  const float s1 = half ? (-2.0f * LOG2E) : (-LOG2E);
  const float s2 = -LOG2E;
  unsigned int* base = ws + lane * 36;
  union { h2 h; unsigned int u; } cv;
  for (int d = 0; d < 16; ++d) {
    cv.h = (h2){ (_Float16)(s1 * W_hh[r1 * HSZ + 2*d]),
                 (_Float16)(s1 * W_hh[r1 * HSZ + 2*d + 1]) };
    base[d] = cv.u;
    cv.h = (h2){ (_Float16)(s2 * W_hh[r2 * HSZ + 2*d]),
                 (_Float16)(s2 * W_hh[r2 * HSZ + 2*d + 1]) };
    base[16 + d] = cv.u;
  }
  union { float f; unsigned int u; } fu;
  fu.f = s1 * (b_ih[r1] + b_hh[r1]); base[32] = fu.u;
  fu.f = s2 * (b_ih[r2] + b_hh[r2]); base[33] = fu.u;
  fu.f = s1 * W_ih[r1];              base[34] = fu.u;
  fu.f = s2 * W_ih[r2];              base[35] = fu.u;
}

// -------- main: 256-thread blocks = 4 independent waves, 1 elem each --------
// R10 math verbatim (absmax 4.88e-4 proven). Change: workgroup packs 4 waves
// so the per-CU workgroup-slot limit (R4-R10: occupancy capped ~11 blocks/CU
// = 33% with 64-thread blocks) stops binding: 1024 blocks -> 4 blocks/CU ->
// 16 waves/CU = 4/SIMD. No inter-wave interaction, no barriers; each wave has
// its own LDS h row.
__global__ __launch_bounds__(256, 4)
void lstm_fused_kernel(const unsigned int* __restrict__ ws,
                       const float* __restrict__ x,
                       const float* __restrict__ W1, const float* __restrict__ b1,
                       const float* __restrict__ W2, const float* __restrict__ b2,
                       const float* __restrict__ W3, const float* __restrict__ b3,
                       float* __restrict__ out)
{
  __shared__ __align__(16) _Float16 hl[4][64];  // per wave: [0..31] h, [32..63] trash

  const int tid  = threadIdx.x;
  const int wave = tid >> 6;             // 0..3: independent element
  const int lane = tid & 63;
  const int half = lane >> 5;            // 0: gates i,f ; 1: gates g,o
  const int elem = blockIdx.x * 4 + wave;

  const float A1 = half ? 2.0f : 1.0f;   // act1 = A1*rcp(1+exp2(z1)) + B1
  const float B1 = half ? -1.0f : 0.0f;  // -> sigm (lower) | tanh (upper)
  const float n2l = -2.0f * LOG2E;

  // ---- per-lane packed weights (32 dwords) + scaled consts ----
  const v4u* wp = reinterpret_cast<const v4u*>(ws + (size_t)lane * 36);
  v4u wq[8];
#pragma unroll
  for (int q = 0; q < 8; ++q) wq[q] = wp[q];
  h2 w1h[16], w2h[16];
#pragma unroll
  for (int q = 0; q < 4; ++q) {
    w1h[4*q+0] = bch2(wq[q].x);   w1h[4*q+1] = bch2(wq[q].y);
    w1h[4*q+2] = bch2(wq[q].z);   w1h[4*q+3] = bch2(wq[q].w);
    w2h[4*q+0] = bch2(wq[4+q].x); w2h[4*q+1] = bch2(wq[4+q].y);
    w2h[4*q+2] = bch2(wq[4+q].z); w2h[4*q+3] = bch2(wq[4+q].w);
  }
  const float* cf = reinterpret_cast<const float*>(ws + (size_t)lane * 36 + 32);
  const float bz1 = cf[0], bz2 = cf[1], wx1 = cf[2], wx2 = cf[3];

  float c = 0.0f;
  hl[wave][lane] = (_Float16)0.0f;       // h0 = 0 (both halves' slots)

  const float* xrow = x + (size_t)elem * TT;
  const v4u* hv = reinterpret_cast<const v4u*>(&hl[wave][0]); // wave-uniform

#pragma unroll 1
  for (int t0 = 0; t0 < TT; t0 += 64) {
    float xc = xrow[t0 + lane];          // coalesced: 64 timesteps per load

#pragma unroll 16
    for (int s = 0; s < 64; ++s) {
      // wave-uniform x_t via v_readlane (SGPR select) — no DS op, no wait
      float xt = __builtin_bit_cast(float,
          __builtin_amdgcn_readlane(__builtin_bit_cast(unsigned, xc), s));

      float a1 = fmaf(xt, wx1, bz1);     // z seeds (bias + x-term)
      float a2 = fmaf(xt, wx2, bz2);

#pragma unroll
      for (int g = 0; g < 4; ++g) {      // h k-chunk [8g, 8g+8) as 4 half2
        v4u hq = hv[g];
        h2 p0 = bch2(hq.x), p1 = bch2(hq.y), p2 = bch2(hq.z), p3 = bch2(hq.w);
        a1 = fdot2(w1h[4*g+0], p0, a1);
        a2 = fdot2(w2h[4*g+0], p0, a2);
        a1 = fdot2(w1h[4*g+1], p1, a1);
        a2 = fdot2(w2h[4*g+1], p1, a2);
        a1 = fdot2(w1h[4*g+2], p2, a1);
        a2 = fdot2(w2h[4*g+2], p2, a2);
        a1 = fdot2(w1h[4*g+3], p3, a1);
        a2 = fdot2(w2h[4*g+3], p3, a2);
      }

      float act1 = fmaf(A1, frcp(1.0f + fexp2(a1)), B1); // sigm(i) | tanh(g)
      float act2 = frcp(1.0f + fexp2(a2));               // sigm(f) | sigm(o)

      float tg = __shfl_xor(act1, 32);   // lower <- tanh(g)   (proven)
      float so = __shfl_xor(act2, 32);   // lower <- sigm(o)

      c = fmaf(act2, c, act1 * tg);      // lower: sigm(f)*c + sigm(i)*tanh(g)
      float r = frcp(1.0f + fexp2(c * n2l));  // tanh(c) = 2r - 1
      float h = fmaf(2.0f, so * r, -so); // lower: sigm(o)*tanh(c)

      hl[wave][lane] = (_Float16)h;      // upper half -> trash slots [32..63]
    }
  }

  // ---- MLP head 32->16->8->1 on final h (this wave's row), per lane ----
  float hf[HSZ];
#pragma unroll
  for (int k = 0; k < HSZ; ++k) hf[k] = (float)hl[wave][k];

  float a1v[16];
#pragma unroll
  for (int rr = 0; rr < 16; ++rr) {
    float acc = b1[rr];
#pragma unroll
    for (int k = 0; k < 32; ++k) acc = fmaf(W1[rr * 32 + k], hf[k], acc);
    a1v[rr] = fmaxf(acc, 0.0f);
  }
  float a2v[8];
#pragma unroll
  for (int rr = 0; rr < 8; ++rr) {
    float acc = b2[rr];
#pragma unroll
    for (int k = 0; k < 16; ++k) acc = fmaf(W2[rr * 16 + k], a1v[k], acc);
    a2v[rr] = fmaxf(acc, 0.0f);
  }
  float o = b3[0];
#pragma unroll
  for (int k = 0; k < 8; ++k) o = fmaf(W3[k], a2v[k], o);

  if (lane == 0) out[elem] = o;
}

extern "C" void kernel_launch(void* const* d_in, const int* in_sizes, int n_in,
                              void* d_out, int out_size, void* d_ws, size_t ws_size,
                              hipStream_t stream) {
  const float* x    = (const float*)d_in[0];
  const float* W_ih = (const float*)d_in[1];
  const float* W_hh = (const float*)d_in[2];
  const float* b_ih = (const float*)d_in[3];
  const float* b_hh = (const float*)d_in[4];
  const float* W1   = (const float*)d_in[5];
  const float* b1   = (const float*)d_in[6];
  const float* W2   = (const float*)d_in[7];
  const float* b2   = (const float*)d_in[8];
  const float* W3   = (const float*)d_in[9];
  const float* b3   = (const float*)d_in[10];
  float* out = (float*)d_out;
  unsigned int* ws = (unsigned int*)d_ws;    // 64*36 dwords = 9216 B

  const int B = in_sizes[0] / TT;            // 4096

  hipLaunchKernelGGL(lstm_prep_kernel, dim3(1), dim3(64), 0, stream,
                     W_ih, W_hh, b_ih, b_hh, ws);
  hipLaunchKernelGGL(lstm_fused_kernel, dim3(B / 4), dim3(256), 0, stream,
                     ws, x, W1, b1, W2, b2, W3, b3, out);
}